// Round 8
// baseline (12151.371 us; speedup 1.0000x reference)
//
#include <hip/hip_runtime.h>

#define NN 512
#define DD 32
#define TT 8192

typedef float v4f __attribute__((ext_vector_type(4)));

constexpr float F_OMEGA = 10.0f;
constexpr float F_DT = 1e-3f;
constexpr float F_TWO_PI = 6.28318530717958647692f;
constexpr float F_INV_TWO_PI = 0.15915494309189533577f;

// Barrier waiting LDS only (lgkmcnt), never vmcnt: the x prefetch loads and
// output stores stay in flight across the per-step sync.
__device__ __forceinline__ void barrier_lgkm() {
    asm volatile("s_waitcnt lgkmcnt(0)\n\ts_barrier" ::: "memory");
}

// Laundered global vector loads: compiler cannot scalarize them (R1/R5
// failure mode), cannot sink them to the use site, and their vmcnt is drained
// only by our counted wait. First load of each batch carries a "memory"
// clobber to pin preceding C-level stores before it (stable vmcnt count).
#define GLD4M(dst, base, off) \
    asm volatile("global_load_dwordx4 %0, %1, off offset:" #off \
                 : "=v"(dst) : "v"(base) : "memory")
#define GLD4(dst, base, off) \
    asm volatile("global_load_dwordx4 %0, %1, off offset:" #off \
                 : "=v"(dst) : "v"(base))
#define GLD1(dst, base) \
    asm volatile("global_load_dword %0, %1, off" : "=v"(dst) : "v"(base))

// One step of a DPP-based wave64 reduction: x += dpp_move(x).
#define DPP_ADD(x, ctrl, rmask)                                                 \
    {                                                                           \
        int _t = __builtin_amdgcn_update_dpp(0, __float_as_int(x),              \
                                             (ctrl), (rmask), 0xf, true);       \
        (x) += __int_as_float(_t);                                              \
    }

__device__ __forceinline__ float wave_reduce_to_lane63(float x) {
    DPP_ADD(x, 0xB1, 0xf);   // + xor1
    DPP_ADD(x, 0x4E, 0xf);   // + xor2
    DPP_ADD(x, 0x141, 0xf);  // + xor4
    DPP_ADD(x, 0x140, 0xf);  // + xor8
    DPP_ADD(x, 0x142, 0xa);  // row_bcast15
    DPP_ADD(x, 0x143, 0xc);  // row_bcast31
    return x;                // lane 63 = full wave sum
}

__device__ __forceinline__ float hsum4(v4f a) {
    return (a.x + a.y) + (a.z + a.w);
}

// Issue the 17-load batch for x[tn] (8x xr, 8x xi, 1x tgt). Broadcast-same-
// address per wave -> one coalesced 16B request each.
__device__ __forceinline__ void issue_batch(
    int tn, const float* Xr, const float* Xi, const float* Tg,
    v4f (&nr)[8], v4f (&ni)[8], float& ntg)
{
    const unsigned long long bxr = (unsigned long long)(Xr + (size_t)tn * DD);
    const unsigned long long bxi = (unsigned long long)(Xi + (size_t)tn * DD);
    const unsigned long long btg = (unsigned long long)(Tg + tn);
    GLD4M(nr[0], bxr, 0);   GLD4(nr[1], bxr, 16);
    GLD4(nr[2], bxr, 32);   GLD4(nr[3], bxr, 48);
    GLD4(nr[4], bxr, 64);   GLD4(nr[5], bxr, 80);
    GLD4(nr[6], bxr, 96);   GLD4(nr[7], bxr, 112);
    GLD4(ni[0], bxi, 0);    GLD4(ni[1], bxi, 16);
    GLD4(ni[2], bxi, 32);   GLD4(ni[3], bxi, 48);
    GLD4(ni[4], bxi, 64);   GLD4(ni[5], bxi, 80);
    GLD4(ni[6], bxi, 96);   GLD4(ni[7], bxi, 112);
    GLD1(ntg, btg);
}

// Tied counted wait for the CURRENT batch. Newer VMEM ops at this point:
// gammas(t-1) + betas(t-1) + outs(t-1) + batch(t+1)x17 + gammas(t) = 21.
#define WAIT_BATCH(cr, ci, tgt, cnt)                                            \
    asm volatile("s_waitcnt vmcnt(" #cnt ")"                                    \
        : "+v"(cr[0]), "+v"(cr[1]), "+v"(cr[2]), "+v"(cr[3]),                   \
          "+v"(cr[4]), "+v"(cr[5]), "+v"(cr[6]), "+v"(cr[7]),                   \
          "+v"(ci[0]), "+v"(ci[1]), "+v"(ci[2]), "+v"(ci[3]),                   \
          "+v"(ci[4]), "+v"(ci[5]), "+v"(ci[6]), "+v"(ci[7]),                   \
          "+v"(tgt) :: "memory")

__device__ __forceinline__ void do_step(
    int t,
    const float* __restrict__ Xr, const float* __restrict__ Xi,
    const float* __restrict__ Tg,
    v4f (&wr4)[8], v4f (&wi4)[8],
    v4f (&cr)[8], v4f (&ci)[8], float& tgt,      // current x (in flight)
    v4f (&nr)[8], v4f (&ni)[8], float& ntg,      // next x destination
    float& phi, float& beta, float& lt, float& err,
    float* __restrict__ outs, float* __restrict__ betas, float* __restrict__ gammas,
    float* sP, int n, int lane, int wid)
{
    // ---- 1. issue prefetch batch for x[t+1] (full step of slack) ----
    int tn = t + 1; tn = (tn < TT) ? tn : (TT - 1);
    issue_batch(tn, Xr, Xi, Tg, nr, ni, ntg);

    // ---- 2. x-independent precompute (fills the in-flight window) ----
    const float gamma = __expf(-0.5f * beta);
    const float dtl = gamma * F_DT;
    lt += dtl;
    const float theta = fmaf(F_OMEGA, lt, phi);
    float rev = theta * F_INV_TWO_PI;
    rev -= floorf(rev);
    const float s = __builtin_amdgcn_sinf(rev);
    const float c = __builtin_amdgcn_cosf(rev);
    const float a_sA = 1.0f - __expf(-2.0f * F_DT * (gamma + 1e-6f));
    const float a_sB = 1.0f - __expf(-F_DT / 0.03f);   // constant-folded

    gammas[t * NN + n] = gamma;   // gamma from OLD beta, per reference

    // ---- 3. counted drain of the current batch (issued one step ago) ----
    WAIT_BATCH(cr, ci, tgt, 21);

    // ---- 4. Z = W @ x, 4 packed v4f accumulator chains (R6 FP order) ----
    v4f Arr = {0,0,0,0}, Aii = {0,0,0,0}, Ari = {0,0,0,0}, Air = {0,0,0,0};
#pragma unroll
    for (int j = 0; j < 8; ++j) {
        Arr += wr4[j] * cr[j];
        Aii += wi4[j] * ci[j];
        Ari += wr4[j] * ci[j];
        Air += wi4[j] * cr[j];
    }
    const float zr = hsum4(Arr) - hsum4(Aii);
    const float zi = hsum4(Ari) + hsum4(Air);

    // Y = |Z| * relu(cos(theta - angle(Z))) == relu(zr*cos + zi*sin)
    const float Y = fmaxf(fmaf(zr, c, zi * s), 0.0f);

    // ---- 5. reduce 512 -> 1: DPP wave sum, 8 partials via LDS ----
    float v = wave_reduce_to_lane63(Y * c);
    if (lane == 63) sP[((t & 1) << 3) + wid] = v;

    // ---- 6. out-independent precompute (off the post-barrier path) ----
    const float inv_t = 1.0f / (fabsf(tgt) + 0.01f);
    const float yy = Y * Y;
    const float g = 0.05f * Y * dtl;
    phi += (2.0f / (float)NN) * (-tgt * s) * dtl;
    phi = phi - F_TWO_PI * floorf(phi * F_INV_TWO_PI);

    barrier_lgkm();

    // ---- 7. out + short scalar feedback chain ----
    const float4* sp4 = (const float4*)(sP + ((t & 1) << 3));
    const float4 p0 = sp4[0], p1 = sp4[1];
    const float out = ((p0.x + p0.y) + (p0.z + p0.w)) +
                      ((p1.x + p1.y) + (p1.z + p1.w));

    const float raw = fabsf(tgt - out);
    err = 0.99f * err + 0.01f * raw;
    const float rel = err * inv_t;
    const float btg = 3.5f * __expf(-5.0f * rel);
    const float a_s = (btg > beta) ? a_sA : a_sB;
    float bnew = beta + a_s * (btg - beta);
    bnew = fminf(fmaxf(bnew, 0.005f), 5.0f);

    // ---- 8. W = W*(1 - (bnew*yy)*dtl) + g*x (packed, same FP order) ----
    const float k = (bnew * yy) * dtl;
    const float m1 = 1.0f - k;
    const v4f m1v = {m1, m1, m1, m1};
    const v4f gv = {g, g, g, g};
#pragma unroll
    for (int j = 0; j < 8; ++j) {
        wr4[j] = wr4[j] * m1v + gv * cr[j];
        wi4[j] = wi4[j] * m1v + gv * ci[j];
    }

    // ---- 9. tail outputs: exactly 2 store instrs here (+1 gamma above) ----
    betas[t * NN + n] = bnew;
    if (lane == 63) outs[t] = out;
    beta = bnew;
}

__global__ __launch_bounds__(512, 2) void deerskin(
    const float* __restrict__ Xr, const float* __restrict__ Xi,
    const float* __restrict__ Tg,
    const float* __restrict__ W0r, const float* __restrict__ W0i,
    const float* __restrict__ Phi0, const float* __restrict__ Beta0,
    float* __restrict__ outs, float* __restrict__ betas, float* __restrict__ gammas)
{
    __shared__ __align__(16) float sP[16];   // double-buffered 8 wave-partials

    const int n = threadIdx.x;
    const int lane = n & 63;
    const int wid = n >> 6;

    // W row in registers as v4f[8] (64 VGPRs per re/im).
    v4f wr4[8], wi4[8];
    {
        const v4f* wr0 = (const v4f*)(W0r + n * DD);
        const v4f* wi0 = (const v4f*)(W0i + n * DD);
#pragma unroll
        for (int j = 0; j < 8; ++j) { wr4[j] = wr0[j]; wi4[j] = wi0[j]; }
    }
    float phi = Phi0[n];
    float beta = Beta0[n];
    float lt = 0.0f;
    float err = 0.0f;

    // x double-buffer in VGPRs; 2x-unrolled loop swaps roles (no copies).
    v4f xa_r[8], xa_i[8], xb_r[8], xb_i[8];
    float tgtA, tgtB;

    // ---- prologue: batch x(0) -> A, full drain ----
    issue_batch(0, Xr, Xi, Tg, xa_r, xa_i, tgtA);
    WAIT_BATCH(xa_r, xa_i, tgtA, 0);
    barrier_lgkm();

    for (int t = 0; t < TT; t += 2) {
        do_step(t,     Xr, Xi, Tg, wr4, wi4,
                xa_r, xa_i, tgtA, xb_r, xb_i, tgtB,
                phi, beta, lt, err, outs, betas, gammas, sP, n, lane, wid);
        do_step(t + 1, Xr, Xi, Tg, wr4, wi4,
                xb_r, xb_i, tgtB, xa_r, xa_i, tgtA,
                phi, beta, lt, err, outs, betas, gammas, sP, n, lane, wid);
    }
}

extern "C" void kernel_launch(void* const* d_in, const int* in_sizes, int n_in,
                              void* d_out, int out_size, void* d_ws, size_t ws_size,
                              hipStream_t stream) {
    const float* Xr    = (const float*)d_in[0];   // [T, D]
    const float* Xi    = (const float*)d_in[1];   // [T, D]
    const float* Tg    = (const float*)d_in[2];   // [T]
    const float* W0r   = (const float*)d_in[3];   // [N, D]
    const float* W0i   = (const float*)d_in[4];   // [N, D]
    const float* Phi0  = (const float*)d_in[5];   // [N]
    const float* Beta0 = (const float*)d_in[6];   // [N]

    float* outs   = (float*)d_out;                // [T]
    float* betas  = outs + TT;                    // [T, N]
    float* gammas = betas + (size_t)TT * NN;      // [T, N]

    deerskin<<<1, NN, 0, stream>>>(Xr, Xi, Tg, W0r, W0i, Phi0, Beta0,
                                   outs, betas, gammas);
}

// Round 10
// 10049.310 us; speedup vs baseline: 1.2092x; 1.2092x over previous
//
#include <hip/hip_runtime.h>

#define NN 512
#define DD 32
#define TT 8192

typedef float v2f __attribute__((ext_vector_type(2)));
typedef __attribute__((address_space(3))) float lds_f;
typedef __attribute__((address_space(3))) void lds_v;
typedef const __attribute__((address_space(1))) void glb_v;

constexpr float F_OMEGA = 10.0f;
constexpr float F_DT = 1e-3f;
constexpr float F_TWO_PI = 6.28318530717958647692f;
constexpr float F_INV_TWO_PI = 0.15915494309189533577f;

// Barrier waiting LDS only (lgkmcnt), never vmcnt: glds prefetches and output
// stores stay in flight across the per-step sync.
__device__ __forceinline__ void barrier_lgkm() {
    asm volatile("s_waitcnt lgkmcnt(0)\n\ts_barrier" ::: "memory");
}

// Async global->LDS stage, vmcnt-tracked (wave-uniform LDS base + lane*4).
__device__ __forceinline__ void glds4(const float* g, lds_f* dst) {
    __builtin_amdgcn_global_load_lds((glb_v*)g, (lds_v*)dst, 4, 0, 0);
}

// Laundered lane-strided LDS read (one instr/wave): not scalarizable, not
// sinkable, invisible to alias analysis (no conservative vmcnt drain).
#define DSR32(dst, addr, off) \
    asm volatile("ds_read_b32 %0, %1 offset:" #off : "=v"(dst) : "v"(addr))
// Tied wait: DS ops complete in-order per wave, so lgkmcnt(0) here is exact.
#define WAIT2(a, b) \
    asm volatile("s_waitcnt lgkmcnt(0)" : "+v"(a), "+v"(b) :: "memory")

// One step of a DPP-based wave64 reduction: x += dpp_move(x).
#define DPP_ADD(x, ctrl, rmask)                                                 \
    {                                                                           \
        int _t = __builtin_amdgcn_update_dpp(0, __float_as_int(x),              \
                                             (ctrl), (rmask), 0xf, true);       \
        (x) += __int_as_float(_t);                                              \
    }

__device__ __forceinline__ float wave_reduce_to_lane63(float x) {
    DPP_ADD(x, 0xB1, 0xf);   // + xor1
    DPP_ADD(x, 0x4E, 0xf);   // + xor2
    DPP_ADD(x, 0x141, 0xf);  // + xor4
    DPP_ADD(x, 0x140, 0xf);  // + xor8
    DPP_ADD(x, 0x142, 0xa);  // row_bcast15
    DPP_ADD(x, 0x143, 0xc);  // row_bcast31
    return x;                // lane 63 = full wave sum
}

// Distribute the lane-strided x register to all lanes as SGPR pairs via the
// VALU lane-crossbar (v_readlane): zero LDS-pipe cost, feeds v_pk_fma as the
// single scalar operand.
__device__ __forceinline__ void unpack_readlane(float vx, v2f (&xr)[16], v2f (&xi)[16]) {
    const int vxi = __float_as_int(vx);
#pragma unroll
    for (int j = 0; j < 16; ++j) {
        xr[j] = v2f{__int_as_float(__builtin_amdgcn_readlane(vxi, 2 * j)),
                    __int_as_float(__builtin_amdgcn_readlane(vxi, 2 * j + 1))};
        xi[j] = v2f{__int_as_float(__builtin_amdgcn_readlane(vxi, 32 + 2 * j)),
                    __int_as_float(__builtin_amdgcn_readlane(vxi, 32 + 2 * j + 1))};
    }
}

__global__ __launch_bounds__(512, 2) void deerskin(
    const float* __restrict__ Xr, const float* __restrict__ Xi,
    const float* __restrict__ Tg,
    const float* __restrict__ W0r, const float* __restrict__ W0i,
    const float* __restrict__ Phi0, const float* __restrict__ Beta0,
    float* __restrict__ outs, float* __restrict__ betas, float* __restrict__ gammas)
{
    // 3 x-staging buffers: [0..31]=xr, [32..63]=xi, [64]=tgt (288B each).
    __shared__ __align__(16) float xbuf[3][72];
    __shared__ __align__(16) float sP[16];   // double-buffered 8 wave-partials

    const int n = threadIdx.x;
    const int lane = n & 63;
    const int wid = n >> 6;

    // W row in registers as d-pair float2s (64 VGPRs total).
    v2f wr[16], wi[16];
    {
        const v2f* wr0 = (const v2f*)(W0r + n * DD);
        const v2f* wi0 = (const v2f*)(W0i + n * DD);
#pragma unroll
        for (int j = 0; j < 16; ++j) { wr[j] = wr0[j]; wi[j] = wi0[j]; }
    }
    float phi = Phi0[n];
    float beta = Beta0[n];
    float lt = 0.0f;
    float err = 0.0f;

    // glds source for wave 0: lanes 0..31 -> Xr row, 32..63 -> Xi row.
    const float* xsrc = ((lane < 32) ? Xr : Xi) + (lane & 31);

    lds_f* pcur = (lds_f*)&xbuf[0][0];
    lds_f* pnxt = (lds_f*)&xbuf[1][0];
    lds_f* pfut = (lds_f*)&xbuf[2][0];

    // x of the CURRENT step, distributed to all lanes (SGPR pairs).
    v2f xr[16], xi[16];
    float tgt;

    // ---- prologue: stage x(0), x(1); drain; load+distribute x(0) ----
    if (wid == 0) {
        glds4(xsrc, pcur);
        glds4(xsrc + DD, pnxt);
        if (lane == 0) {
            glds4(Tg, pcur + 64);
            glds4(Tg + 1, pnxt + 64);
        }
        asm volatile("s_waitcnt vmcnt(0)" ::: "memory");
    }
    barrier_lgkm();
    {
        const unsigned lcur = (unsigned)(unsigned long long)pcur;
        float vx, vtg;
        DSR32(vx, lcur + 4u * (unsigned)lane, 0);
        DSR32(vtg, lcur, 256);
        WAIT2(vx, vtg);
        unpack_readlane(vx, xr, xi);
        tgt = vtg;
    }

    for (int t = 0; t < TT; ++t) {
        // ---- 1. stage x(t+2) (wave 0; drained by the counted wait below) ----
        if (wid == 0) {
            int tf = t + 2; tf = (tf < TT) ? tf : (TT - 1);
            glds4(xsrc + (size_t)tf * DD, pfut);
            if (lane == 0) glds4(Tg + tf, pfut + 64);
        }

        // ---- 2. x-independent precompute ----
        const float gamma = __expf(-0.5f * beta);
        const float dtl = gamma * F_DT;
        lt += dtl;
        const float theta = fmaf(F_OMEGA, lt, phi);
        float rev = theta * F_INV_TWO_PI;
        rev -= floorf(rev);
        const float s = __builtin_amdgcn_sinf(rev);
        const float c = __builtin_amdgcn_cosf(rev);
        const float a_sA = 1.0f - __expf(-2.0f * F_DT * (gamma + 1e-6f));
        const float a_sB = 1.0f - __expf(-F_DT / 0.03f);   // constant-folded

        // ---- 3. Z = W @ x, 4 packed chains (R4 FP order; x = SGPR pairs) ----
        v2f Arr = {0.f,0.f}, Aii = {0.f,0.f}, Ari = {0.f,0.f}, Air = {0.f,0.f};
#pragma unroll
        for (int j = 0; j < 16; ++j) {
            Arr += wr[j] * xr[j];
            Aii += wi[j] * xi[j];
            Ari += wr[j] * xi[j];
            Air += wi[j] * xr[j];
        }
        const float zr = (Arr.x + Arr.y) - (Aii.x + Aii.y);
        const float zi = (Ari.x + Ari.y) + (Air.x + Air.y);

        // Y = |Z| * relu(cos(theta - angle(Z))) == relu(zr*cos + zi*sin)
        const float Y = fmaxf(fmaf(zr, c, zi * s), 0.0f);

        // ---- 4. reduce 512 -> 1: DPP wave sum, 8 partials via LDS ----
        float v = wave_reduce_to_lane63(Y * c);
        if (lane == 63) sP[((t & 1) << 3) + wid] = v;

        // ---- 5. out-independent precompute (off the post-barrier path) ----
        const float inv_t = 1.0f / (fabsf(tgt) + 0.01f);
        const float yy = Y * Y;
        const float g = 0.05f * Y * dtl;
        phi += (2.0f / (float)NN) * (-tgt * s) * dtl;
        phi = phi - F_TWO_PI * floorf(phi * F_INV_TWO_PI);

        // ---- 6. counted drain of glds(t+1) (wave 0), then sync.
        // Newer than glds(t+1): stores(t-1) x3 + glds(t+2) x2 = 5.
        if (wid == 0) asm volatile("s_waitcnt vmcnt(5)" ::: "memory");
        barrier_lgkm();

        // ---- 7. issue next-x read (pnxt complete: counted-wait + barrier) ----
        float vx, vtg;
        {
            const unsigned lnxt = (unsigned)(unsigned long long)pnxt;
            DSR32(vx, lnxt + 4u * (unsigned)lane, 0);
            DSR32(vtg, lnxt, 256);
        }

        // ---- 8. out + short scalar feedback chain ----
        const float4* sp4 = (const float4*)(sP + ((t & 1) << 3));
        const float4 p0 = sp4[0], p1 = sp4[1];
        const float out = ((p0.x + p0.y) + (p0.z + p0.w)) +
                          ((p1.x + p1.y) + (p1.z + p1.w));

        const float raw = fabsf(tgt - out);
        err = 0.99f * err + 0.01f * raw;
        const float rel = err * inv_t;
        const float btg = 3.5f * __expf(-5.0f * rel);
        const float a_s = (btg > beta) ? a_sA : a_sB;
        float bnew = beta + a_s * (btg - beta);
        bnew = fminf(fmaxf(bnew, 0.005f), 5.0f);

        // ---- 9. W = W*(1 - (bnew*yy)*dtl) + g*x (packed, R4 FP order) ----
        const float k = (bnew * yy) * dtl;
        const float m1 = 1.0f - k;
        const v2f m1v = {m1, m1};
        const v2f gv = {g, g};
#pragma unroll
        for (int j = 0; j < 16; ++j) {
            wr[j] = wr[j] * m1v + gv * xr[j];
            wi[j] = wi[j] * m1v + gv * xi[j];
        }

        // ---- 10. outputs: exactly 3 store instrs per wave per step ----
        gammas[t * NN + n] = gamma;   // gamma from OLD beta, per reference
        betas[t * NN + n] = bnew;
        if (lane == 63) outs[t] = out;
        beta = bnew;

        // ---- 11. distribute x(t+1) for the next step (VALU crossbar) ----
        WAIT2(vx, vtg);
        unpack_readlane(vx, xr, xi);
        tgt = vtg;

        // ---- 12. rotate staging buffers ----
        lds_f* tmp = pcur; pcur = pnxt; pnxt = pfut; pfut = tmp;
    }
}

extern "C" void kernel_launch(void* const* d_in, const int* in_sizes, int n_in,
                              void* d_out, int out_size, void* d_ws, size_t ws_size,
                              hipStream_t stream) {
    const float* Xr    = (const float*)d_in[0];   // [T, D]
    const float* Xi    = (const float*)d_in[1];   // [T, D]
    const float* Tg    = (const float*)d_in[2];   // [T]
    const float* W0r   = (const float*)d_in[3];   // [N, D]
    const float* W0i   = (const float*)d_in[4];   // [N, D]
    const float* Phi0  = (const float*)d_in[5];   // [N]
    const float* Beta0 = (const float*)d_in[6];   // [N]

    float* outs   = (float*)d_out;                // [T]
    float* betas  = outs + TT;                    // [T, N]
    float* gammas = betas + (size_t)TT * NN;      // [T, N]

    deerskin<<<1, NN, 0, stream>>>(Xr, Xi, Tg, W0r, W0i, Phi0, Beta0,
                                   outs, betas, gammas);
}